// Round 14
// baseline (36.040 us; speedup 1.0000x reference)
//
#include <hip/hip_runtime.h>
#include <math.h>

#define SM1 2047.0f

// ws float-index layout:
#define WS_P     0       // poles[32]            (published by k2 blk0)
#define WS_IDEN  32      // d/(1-d)
#define WS_PF    64      // spectral filter
#define WS_WIDX  96      // (int) W
#define WS_WSUM  128     // wsum[32 k][32 o]              (1024)
#define WS_PART  1312    // channel partials [64 blk][4]  (256)
#define WS_PXS   2048    // xsum partials [8 b][8 q][2048] (131072)
#define WS_Y     133120  // y[8][32 k][2048 t] combined   (524288)
// top = 657408 floats = 2.5 MiB

// K1: blocks 0-63: pure streaming x-read (proven R13). Blocks 64-67: wsum.
__global__ __launch_bounds__(256) void k1(const float* __restrict__ x,
                                          const float* __restrict__ wla,
                                          const float* __restrict__ wph,
                                          float* __restrict__ ws) {
    int blk = blockIdx.x, tid = threadIdx.x;
    if (blk >= 64) {                       // ---- wsum blocks ----
        int k = ((blk - 64) << 3) + (tid >> 5);
        int o = tid & 31;
        float a = 0.f;
#pragma unroll 4
        for (int c = 0; c < 32; ++c) {
            int e = (((k << 5) + c) << 5) + o;
            a += cosf(wph[e]) / (1.0f + expf(-wla[e]));
        }
        ws[WS_WSUM + (k << 5) + o] = a;
        return;
    }
    int b = blk >> 3, q = blk & 7;         // rows c = 4q .. 4q+3 of batch b
    const float4* x4 = (const float4*)x + ((size_t)(((b << 5) + (q << 2))) << 9);
    __shared__ float pr[8][4];
    float4 ae = make_float4(0.f, 0.f, 0.f, 0.f);
    float4 ao = make_float4(0.f, 0.f, 0.f, 0.f);
    int wid = tid >> 6;
#pragma unroll
    for (int it = 0; it < 8; ++it) {
        float4 v = x4[(it << 8) + tid];
        float pc = (v.x + v.y) + (v.z + v.w);
        if (it & 1) { ao.x += v.x; ao.y += v.y; ao.z += v.z; ao.w += v.w; }
        else        { ae.x += v.x; ae.y += v.y; ae.z += v.z; ae.w += v.w; }
        for (int off = 32; off; off >>= 1) pc += __shfl_xor(pc, off, 64);
        if ((tid & 63) == 0) pr[it][wid] = pc;
    }
    float4* pxs4 = (float4*)(ws + WS_PXS) + ((size_t)(((b << 3) + q)) << 9);
    pxs4[tid] = ae;
    pxs4[256 + tid] = ao;
    __syncthreads();
    if (tid < 4) {
        float m = 0.f;
#pragma unroll
        for (int w = 0; w < 4; ++w) m += pr[(tid << 1)][w] + pr[(tid << 1) + 1][w];
        ws[WS_PART + (blk << 2) + tid] = m;
    }
}

// K2: 32 blocks (b,kq) x 512 thr (dir halves). Redundant prep, pass A both
// dirs in parallel, LDS carry scan, pass B fwd->LDS tile, bwd adds, combine
// streams combined y to global. blk0 publishes per-k consts for k3.
__global__ __launch_bounds__(512) void k2(const float* __restrict__ c_star,
                                          const float* __restrict__ dt,
                                          const float* __restrict__ lp,
                                          const float* __restrict__ pw,
                                          const float* __restrict__ pb,
                                          float* __restrict__ ws) {
    __shared__ float xr[2048];
    __shared__ float yt[32][8][65];        // bank = (8*chunk+kk+i)%32 -> 2-way
    __shared__ float carr[2][32][9];
    __shared__ float xm[32], cP[32], cD[32], cDW1[32], cDL[32], cPF[32], cIDEN[32];
    __shared__ int cWsh;
    int tid = threadIdx.x, blk = blockIdx.x;
    int b = blk >> 2, kq = blk & 3;

    for (int i = tid; i < 2048; i += 512) {        // xr = sum of 8 q-partials
        float s8 = 0.f;
#pragma unroll
        for (int q = 0; q < 8; ++q) s8 += ws[WS_PXS + (((b << 3) + q) << 11) + i];
        xr[i] = s8;
    }
    if (tid < 32) {
        float m = 0.f;
#pragma unroll
        for (int bb = 0; bb < 8; ++bb) m += ws[WS_PART + (bb << 5) + tid];
        xm[tid] = m * (1.0f / 16384.0f);
    }
    __syncthreads();
    if (tid < 32) {
        int k = tid;
        float mc = c_star[0];
        for (int b2 = 1; b2 < 8; ++b2) mc = fmaxf(mc, c_star[b2]);
        float mdn = mc * dt[0];                         // CAUSAL_SAFETY = 1
        int W = (int)(mdn * SM1);
        while (W + 1 <= 2047 && (float)(W + 1) / SM1 <= mdn) ++W;
        while (W > 0 && (float)W / SM1 > mdn) --W;
        W = min(max(W, 0), 2047);
        if (k == 0) cWsh = W;
        float accp = pb[k];
        for (int c = 0; c < 32; ++c) accp += xm[c] * pw[(c << 5) + k];
        float z = lp[k] + 0.1f * tanhf(accp);           // POLE_OFF_SCALE
        float p = log1pf(expf(z));                      // softplus
        p = fminf(fmaxf(p, 0.1f), 100.0f);
        float d = expf(-p / SM1);
        cP[k]   = p;
        cD[k]   = d;
        cDW1[k] = expf(-p * (float)(W + 1) / SM1);
        cDL[k]  = expf(-p * 64.0f / SM1);
        float kn = (float)k / 31.0f;
        cPF[k]  = expf(-4.0f * kn * kn);                // FILTER_STRENGTH
        cIDEN[k] = d / (-expm1f(-p / SM1));             // d/(1-d)
        if (blk == 0) {                                 // publish for k3
            ws[WS_P + k]    = p;
            ws[WS_IDEN + k] = cIDEN[k];
            ws[WS_PF + k]   = cPF[k];
            if (k == 0) ((int*)ws)[WS_WIDX] = W;
        }
    }
    __syncthreads();

    int dir = tid >> 8, lid = tid & 255;
    int chunk = lid >> 3, kk = lid & 7;
    int k = (kq << 3) + kk;
    float d = cD[k], dw1 = cDW1[k], dL = cDL[k];
    int W = cWsh;
    float st = 0.f;
    if (dir == 0) {
        int t0 = chunk << 6;
#pragma unroll
        for (int i = 0; i < 64; ++i) {
            int t = t0 + i;
            float u = xr[t];
            int tl = t - W - 1;
            if (tl >= 0) u = fmaf(-dw1, xr[tl], u);
            st = fmaf(d, st, u);
        }
    } else {
        int t1 = (chunk << 6) + 63;
#pragma unroll
        for (int i = 0; i < 64; ++i) {
            int t = t1 - i;
            float u = xr[t];
            int th = t + W + 1;
            if (th <= 2047) u = fmaf(-dw1, xr[th], u);
            st = fmaf(d, st, u);
        }
    }
    // weighted inclusive Hillis-Steele over chunks (both dirs together)
    int sidx = (dir == 0) ? chunk : 31 - chunk;
    carr[dir][sidx][kk] = st;
    float m = dL, cur = st;
    for (int off = 1; off < 32; off <<= 1) {
        __syncthreads();
        float prev = (sidx >= off) ? carr[dir][sidx - off][kk] : 0.f;
        __syncthreads();
        cur = fmaf(m, prev, cur);
        carr[dir][sidx][kk] = cur;
        m = m * m;
    }
    __syncthreads();
    float cin = (sidx == 0) ? 0.f : carr[dir][sidx - 1][kk];

    // pass B: fwd -> yt, barrier, bwd adds (st - x), barrier, combine stream
    if (dir == 0) {
        st = cin;
        int t0 = chunk << 6;
#pragma unroll
        for (int i = 0; i < 64; ++i) {
            int t = t0 + i;
            float u = xr[t];
            int tl = t - W - 1;
            if (tl >= 0) u = fmaf(-dw1, xr[tl], u);
            st = fmaf(d, st, u);
            yt[chunk][kk][i] = st;
        }
    }
    __syncthreads();
    if (dir == 1) {
        st = cin;
        int t1 = (chunk << 6) + 63;
#pragma unroll
        for (int i = 0; i < 64; ++i) {
            int t = t1 - i;
            float u = xr[t];
            int th = t + W + 1;
            if (th <= 2047) u = fmaf(-dw1, xr[th], u);
            st = fmaf(d, st, u);
            yt[chunk][kk][63 - i] += st - xr[t];
        }
    }
    __syncthreads();
    {
        int w = tid >> 6, l = tid & 63;
        float* yg = ws + WS_Y + (((size_t)((b << 5) + (kq << 3) + w)) << 11);
#pragma unroll
        for (int j = 0; j < 32; ++j)
            yg[(j << 6) + l] = yt[j][w][l];
    }
}

// K3: sc(k,t) inline (one element/thread); out[b,o,t] = sum_k y*sc * wsum
__global__ __launch_bounds__(1024) void k3(const float* __restrict__ ws,
                                           float* __restrict__ out) {
    __shared__ float wl[1024];
    __shared__ float yts[32 * 33];
    int tid = threadIdx.x;
    int b = blockIdx.x >> 6;
    int t0 = (blockIdx.x & 63) << 5;
    wl[tid] = ws[WS_WSUM + tid];
    {
        int k = tid >> 5, tt = tid & 31;
        int t = t0 + tt;
        float p = ws[WS_P + k], iden = ws[WS_IDEN + k], pf = ws[WS_PF + k];
        int W = ((const int*)ws)[WS_WIDX];
        int n1 = min(W, t), n2 = min(W, 2047 - t);
        float g1 = -iden * expm1f(-p * (float)n1 * (1.0f / SM1));
        float g2 = -iden * expm1f(-p * (float)n2 * (1.0f / SM1));
        float sc = pf / (1.0f + g1 + g2);
        yts[tt * 33 + k] = ws[WS_Y + (((size_t)((b << 5) + k)) << 11) + t] * sc;
    }
    __syncthreads();
    {
        int o = tid >> 5, tt = tid & 31;
        float acc = 0.f;
#pragma unroll
        for (int kk = 0; kk < 32; ++kk)
            acc = fmaf(yts[tt * 33 + kk], wl[(kk << 5) + o], acc);
        out[((size_t)((b << 5) + o) << 11) + t0 + tt] = acc;
    }
}

extern "C" void kernel_launch(void* const* d_in, const int* in_sizes, int n_in,
                              void* d_out, int out_size, void* d_ws, size_t ws_size,
                              hipStream_t stream) {
    const float* x      = (const float*)d_in[0];
    const float* c_star = (const float*)d_in[1];
    const float* dt     = (const float*)d_in[2];
    // d_in[3] = dx_star (unused)
    const float* wla    = (const float*)d_in[4];
    const float* wph    = (const float*)d_in[5];
    const float* lp     = (const float*)d_in[6];
    const float* pw     = (const float*)d_in[7];
    const float* pb     = (const float*)d_in[8];
    float* out = (float*)d_out;
    float* ws  = (float*)d_ws;

    k1<<<68,  256,  0, stream>>>(x, wla, wph, ws);
    k2<<<32,  512,  0, stream>>>(c_star, dt, lp, pw, pb, ws);
    k3<<<512, 1024, 0, stream>>>(ws, out);
}

// Round 15
// 31.076 us; speedup vs baseline: 1.1597x; 1.1597x over previous
//
#include <hip/hip_runtime.h>
#include <math.h>

#define SM1 2047.0f

// ws float-index layout:
#define WS_P     0       // poles[32]   (published by k2 blk0)
#define WS_IDEN  32      // d/(1-d)
#define WS_PF    64      // spectral filter
#define WS_WIDX  96      // (int) W
#define WS_WSUM  128     // wsum[32 k][32 o]               (1024)
#define WS_PART  1312    // channel partials [64 blk][4]   (256)
#define WS_PXS   2048    // xsum partials [8 b][8 q][2048] (131072)
#define WS_YF    133120  // yF[8][32 k][2048 t]            (524288)
#define WS_YB    657408  // yB[8][32 k][2048 t]            (524288)
// top = 1181696 floats = 4.51 MiB

// K1: blocks 0-63: pure streaming x-read (proven R13). Blocks 64-67: wsum.
__global__ __launch_bounds__(256) void k1(const float* __restrict__ x,
                                          const float* __restrict__ wla,
                                          const float* __restrict__ wph,
                                          float* __restrict__ ws) {
    int blk = blockIdx.x, tid = threadIdx.x;
    if (blk >= 64) {                       // ---- wsum blocks ----
        int k = ((blk - 64) << 3) + (tid >> 5);
        int o = tid & 31;
        float a = 0.f;
#pragma unroll 4
        for (int c = 0; c < 32; ++c) {
            int e = (((k << 5) + c) << 5) + o;
            a += cosf(wph[e]) / (1.0f + expf(-wla[e]));
        }
        ws[WS_WSUM + (k << 5) + o] = a;
        return;
    }
    int b = blk >> 3, q = blk & 7;         // rows c = 4q .. 4q+3 of batch b
    const float4* x4 = (const float4*)x + ((size_t)(((b << 5) + (q << 2))) << 9);
    __shared__ float pr[8][4];
    float4 ae = make_float4(0.f, 0.f, 0.f, 0.f);
    float4 ao = make_float4(0.f, 0.f, 0.f, 0.f);
    int wid = tid >> 6;
#pragma unroll
    for (int it = 0; it < 8; ++it) {       // row = it>>1, col half = it&1
        float4 v = x4[(it << 8) + tid];
        float pc = (v.x + v.y) + (v.z + v.w);
        if (it & 1) { ao.x += v.x; ao.y += v.y; ao.z += v.z; ao.w += v.w; }
        else        { ae.x += v.x; ae.y += v.y; ae.z += v.z; ae.w += v.w; }
        for (int off = 32; off; off >>= 1) pc += __shfl_xor(pc, off, 64);
        if ((tid & 63) == 0) pr[it][wid] = pc;
    }
    float4* pxs4 = (float4*)(ws + WS_PXS) + ((size_t)(((b << 3) + q)) << 9);
    pxs4[tid] = ae;                        // cols [0,1024)
    pxs4[256 + tid] = ao;                  // cols [1024,2048)
    __syncthreads();
    if (tid < 4) {                         // channel c = 4q + tid
        float m = 0.f;
#pragma unroll
        for (int w = 0; w < 4; ++w) m += pr[(tid << 1)][w] + pr[(tid << 1) + 1][w];
        ws[WS_PART + (blk << 2) + tid] = m;
    }
}

// K2: 64 blocks (b, dir, kq), 256 thr = 32 chunks x 8 k. Redundant prep
// (PART -> xmean -> poles -> consts); xr = sum of 8 PXS partials; pass A
// (carries only), LDS weighted Hillis-Steele, pass B rescan + float4 stores.
// Block 0 publishes per-k consts for K3.
__global__ __launch_bounds__(256) void k2(const float* __restrict__ c_star,
                                          const float* __restrict__ dt,
                                          const float* __restrict__ lp,
                                          const float* __restrict__ pw,
                                          const float* __restrict__ pb,
                                          float* __restrict__ ws) {
    __shared__ float xr[2048];
    __shared__ float carr[32][9];
    __shared__ float xm[32], cP[32], cD[32], cDW1[32], cDL[32], cPF[32], cIDEN[32];
    __shared__ int cWsh;
    int tid = threadIdx.x, blk = blockIdx.x;
    if (tid < 32) {
        float m = 0.f;
#pragma unroll
        for (int b = 0; b < 8; ++b) m += ws[WS_PART + (b << 5) + tid];
        xm[tid] = m * (1.0f / 16384.0f);
    }
    __syncthreads();
    if (tid < 32) {
        int k = tid;
        float mc = c_star[0];
        for (int b2 = 1; b2 < 8; ++b2) mc = fmaxf(mc, c_star[b2]);
        float mdn = mc * dt[0];                         // CAUSAL_SAFETY = 1
        int W = (int)(mdn * SM1);
        while (W + 1 <= 2047 && (float)(W + 1) / SM1 <= mdn) ++W;
        while (W > 0 && (float)W / SM1 > mdn) --W;
        W = min(max(W, 0), 2047);
        if (k == 0) cWsh = W;
        float accp = pb[k];
        for (int c = 0; c < 32; ++c) accp += xm[c] * pw[(c << 5) + k];
        float z = lp[k] + 0.1f * tanhf(accp);           // POLE_OFF_SCALE
        float p = log1pf(expf(z));                      // softplus
        p = fminf(fmaxf(p, 0.1f), 100.0f);
        float d = expf(-p / SM1);
        cP[k]   = p;
        cD[k]   = d;
        cDW1[k] = expf(-p * (float)(W + 1) / SM1);
        cDL[k]  = expf(-p * 64.0f / SM1);
        float kn = (float)k / 31.0f;
        cPF[k]  = expf(-4.0f * kn * kn);                // FILTER_STRENGTH
        cIDEN[k] = d / (-expm1f(-p / SM1));             // d/(1-d)
        if (blk == 0) {                                 // publish for K3
            ws[WS_P + k]    = p;
            ws[WS_IDEN + k] = cIDEN[k];
            ws[WS_PF + k]   = cPF[k];
            if (k == 0) ((int*)ws)[WS_WIDX] = W;
        }
    }
    __syncthreads();
    int W = cWsh;

    // ---- scan blocks: blk = b*8 + dir*4 + kq ----
    int b = blk >> 3, dir = (blk >> 2) & 1, kq = blk & 3;
#pragma unroll
    for (int j = 0; j < 8; ++j) {          // xr = sum of 8 q-partials
        int idx = (j << 8) + tid;
        float s8 = 0.f;
#pragma unroll
        for (int q = 0; q < 8; ++q) s8 += ws[WS_PXS + (((b << 3) + q) << 11) + idx];
        xr[idx] = s8;
    }
    __syncthreads();
    int chunk = tid >> 3, kk = tid & 7;
    int k = (kq << 3) + kk;
    float d = cD[k], dw1 = cDW1[k], dL = cDL[k];
    float st = 0.f;
    if (dir == 0) {
        int t0 = chunk << 6;
#pragma unroll
        for (int i = 0; i < 64; ++i) {
            int t = t0 + i;
            float u = xr[t];
            int tl = t - W - 1;
            if (tl >= 0) u = fmaf(-dw1, xr[tl], u);
            st = fmaf(d, st, u);
        }
    } else {
        int t1 = (chunk << 6) + 63;
#pragma unroll
        for (int i = 0; i < 64; ++i) {
            int t = t1 - i;
            float u = xr[t];
            int th = t + W + 1;
            if (th <= 2047) u = fmaf(-dw1, xr[th], u);
            st = fmaf(d, st, u);
        }
    }
    // weighted inclusive Hillis-Steele over chunks: T = loc + dL * T_prev
    int sidx = (dir == 0) ? chunk : 31 - chunk;
    carr[sidx][kk] = st;
    float m = dL, cur = st;
    for (int off = 1; off < 32; off <<= 1) {
        __syncthreads();
        float prev = (sidx >= off) ? carr[sidx - off][kk] : 0.f;
        __syncthreads();
        cur = fmaf(m, prev, cur);
        carr[sidx][kk] = cur;
        m = m * m;
    }
    __syncthreads();
    float cin = (sidx == 0) ? 0.f : carr[sidx - 1][kk];
    // pass B: rescan seeded with cin; raw values, float4-buffered stores
    float* yo = ws + ((dir == 0) ? WS_YF : WS_YB) + (((size_t)((b << 5) + k)) << 11);
    float4 v4;
    st = cin;
    if (dir == 0) {
        int t0 = chunk << 6;
#pragma unroll
        for (int i = 0; i < 64; ++i) {
            int t = t0 + i;
            float u = xr[t];
            int tl = t - W - 1;
            if (tl >= 0) u = fmaf(-dw1, xr[tl], u);
            st = fmaf(d, st, u);
            int ph = i & 3;
            if (ph == 0) v4.x = st; else if (ph == 1) v4.y = st;
            else if (ph == 2) v4.z = st;
            else { v4.w = st; *(float4*)(yo + (t & ~3)) = v4; }
        }
    } else {
        int t1 = (chunk << 6) + 63;
#pragma unroll
        for (int i = 0; i < 64; ++i) {
            int t = t1 - i;
            float u = xr[t];
            int th = t + W + 1;
            if (th <= 2047) u = fmaf(-dw1, xr[th], u);
            st = fmaf(d, st, u);
            float val = st - xr[t];
            int ph = t & 3;
            if (ph == 3) v4.w = val; else if (ph == 2) v4.z = val;
            else if (ph == 1) v4.y = val;
            else { v4.x = val; *(float4*)(yo + t) = v4; }
        }
    }
}

// K3: sc(k,t) inline (one element/thread, proven R14);
//     out[b,o,t] = sum_k (yF+yB)*sc * wsum[k,o]
__global__ __launch_bounds__(1024) void k3(const float* __restrict__ ws,
                                           float* __restrict__ out) {
    __shared__ float wl[1024];
    __shared__ float yts[32 * 33];
    int tid = threadIdx.x;
    int b = blockIdx.x >> 6;
    int t0 = (blockIdx.x & 63) << 5;
    wl[tid] = ws[WS_WSUM + tid];
    {
        int k = tid >> 5, tt = tid & 31;
        int t = t0 + tt;
        float p = ws[WS_P + k], iden = ws[WS_IDEN + k], pf = ws[WS_PF + k];
        int W = ((const int*)ws)[WS_WIDX];
        int n1 = min(W, t), n2 = min(W, 2047 - t);
        float g1 = -iden * expm1f(-p * (float)n1 * (1.0f / SM1));
        float g2 = -iden * expm1f(-p * (float)n2 * (1.0f / SM1));
        float sc = pf / (1.0f + g1 + g2);
        size_t yi = (((size_t)((b << 5) + k)) << 11) + t;
        yts[tt * 33 + k] = (ws[WS_YF + yi] + ws[WS_YB + yi]) * sc;
    }
    __syncthreads();
    {
        int o = tid >> 5, tt = tid & 31;
        float acc = 0.f;
#pragma unroll
        for (int kk = 0; kk < 32; ++kk)
            acc = fmaf(yts[tt * 33 + kk], wl[(kk << 5) + o], acc);
        out[((size_t)((b << 5) + o) << 11) + t0 + tt] = acc;
    }
}

extern "C" void kernel_launch(void* const* d_in, const int* in_sizes, int n_in,
                              void* d_out, int out_size, void* d_ws, size_t ws_size,
                              hipStream_t stream) {
    const float* x      = (const float*)d_in[0];
    const float* c_star = (const float*)d_in[1];
    const float* dt     = (const float*)d_in[2];
    // d_in[3] = dx_star (unused)
    const float* wla    = (const float*)d_in[4];
    const float* wph    = (const float*)d_in[5];
    const float* lp     = (const float*)d_in[6];
    const float* pw     = (const float*)d_in[7];
    const float* pb     = (const float*)d_in[8];
    float* out = (float*)d_out;
    float* ws  = (float*)d_ws;

    k1<<<68,  256,  0, stream>>>(x, wla, wph, ws);
    k2<<<64,  256,  0, stream>>>(c_star, dt, lp, pw, pb, ws);
    k3<<<512, 1024, 0, stream>>>(ws, out);
}